// Round 7
// baseline (202.374 us; speedup 1.0000x reference)
//
#include <hip/hip_runtime.h>

#define CH   288
#define GRPS 32
#define CPG  9
#define IMH  64
#define IMW  64
#define HW   4096
#define NB   8
#define NPX  (NB * HW)     // 32768 total pixel rows
#define BN_EPS 1e-5f
#define NSLOT 64

typedef short bf16x8 __attribute__((ext_vector_type(8)));
typedef float f32x4  __attribute__((ext_vector_type(4)));

// ws layout (bytes)
#define TT_OFF   0u            // tmpT bf16, K-slice-tiled (see below), 18,874,368 B
#define WIB_OFF  18874368u     // WiT  bf16 K-tiled [9][288][64B]
#define WOS_OFF  19040256u     // WosT bf16 K-tiled; ALSO stat slots (64x576 f32) pre-k_fold
#define SC_OFF   19208448u     // scale f32 [288]
#define SH_OFF   19209600u     // shift f32 [288]
#define BO2_OFF  19210752u     // folded bias f32 [288]

// Tiled layouts (offsets in SHORTS):
//  WiT/WosT: slice kk (0..8) = 288 rows x 64 B contiguous:
//     off = kk*9216 + row*32 + slot*8 ; slot holds k-chunk (slot ^ swz(row)),
//     swz(row) = (row>>1)&3.   Each staged 1 KB segment is CONTIGUOUS.
//  tmpT: pixel tile P = px/32 (1024 tiles):
//     off = P*9216 + kk*1024 + (px%32)*32 + slot*8 ; same slot rule.

__device__ __forceinline__ unsigned short f2b(float f) {
    unsigned int u = __float_as_uint(f);
    return (unsigned short)((u + 0x7fffu + ((u >> 16) & 1u)) >> 16);
}
__device__ __forceinline__ float b2f(unsigned short h) {
    return __uint_as_float(((unsigned int)h) << 16);
}

// async global->LDS, 16B per lane; dst = wave-uniform base + lane*16
#define GLDS(g, l) __builtin_amdgcn_global_load_lds( \
    (const __attribute__((address_space(1))) void*)(g), \
    (__attribute__((address_space(3))) void*)(l), 16, 0, 0)

// compile-time scheduling fence: nothing crosses (guide rule #18)
#define SFENCE __builtin_amdgcn_sched_barrier(0)

__device__ __forceinline__ f32x4 mfma16(bf16x8 a, bf16x8 b, f32x4 c) {
    return __builtin_amdgcn_mfma_f32_16x16x32_bf16(a, b, c, 0, 0, 0);
}

// ---------------------------------------------------------------------------
// K0b: Wi f32 -> WiT (K-tiled, pre-swizzled). 288*36 = 10368 16B-chunks.
// ---------------------------------------------------------------------------
__global__ __launch_bounds__(256) void k_cvt_wi(const float* __restrict__ Wi,
                                                unsigned short* __restrict__ WiT) {
    const int id = blockIdx.x * 256 + threadIdx.x;
    if (id >= 288 * 36) return;
    const int row  = id / 36;
    const int rest = id - row * 36;
    const int kk   = rest >> 2;
    const int slot = rest & 3;
    const int c0   = kk * 32 + ((slot ^ ((row >> 1) & 3)) << 3);
    const float4 a = *(const float4*)(Wi + (size_t)row * CH + c0);
    const float4 b = *(const float4*)(Wi + (size_t)row * CH + c0 + 4);
    unsigned short h[8] = {f2b(a.x), f2b(a.y), f2b(a.z), f2b(a.w),
                           f2b(b.x), f2b(b.y), f2b(b.z), f2b(b.w)};
    *(uint4*)(WiT + (size_t)kk * 9216 + row * 32 + slot * 8) = *(const uint4*)h;
}

// ---------------------------------------------------------------------------
// K1: pipelined MFMA GEMM1 + fused BN stats.
//   tmp[px][c] = relu(dot(x[px][:], Wi[c][:]) + bi[c])  -> tmpT (tiled bf16)
// Block: 32 px x 288 c, 4 waves; wave = 16 px x 144 c (acc[9]).
// X fragments held in REGISTERS (72 scalar f32 loads/lane, no k_transpose,
// no X LDS). W double-buffered BK=32, contiguous-1KB GLDS, counted vmcnt.
// Phase boundaries pinned with sched_barrier(0) (raw s_barrier is not an
// IR memory fence; full unroll exposed ds_read-hoist race in R6).
// ---------------------------------------------------------------------------
#define WSL 18432   // bytes per W slice buffer
__global__ __launch_bounds__(256, 4) void k_gemm1(const unsigned short* __restrict__ WiT,
                                                  const float* __restrict__ bi,
                                                  const float* __restrict__ x,
                                                  unsigned short* __restrict__ tmpT,
                                                  float* __restrict__ slots) {
    __shared__ char smc[2 * WSL];   // 36864 B

    const int tid  = threadIdx.x;
    const int wave = tid >> 6;
    const int lane = tid & 63;
    const int q    = lane >> 4;
    const int r    = lane & 15;
    const int pxh  = wave & 1;      // 16-px half
    const int chh  = wave >> 1;     // 144-c half
    const int p0   = blockIdx.x * 32;
    const int bidb = p0 >> 12;                       // batch
    const int pix  = (p0 & 4095) + pxh * 16 + r;     // pixel within image

    // ---- A-fragments from x directly: frag[kk] = ch {kk*32+q*8..+8} @ pix ----
    bf16x8 frag[9];
    const float* xs = x + (size_t)(bidb * CH + q * 8) * HW + pix;
    #pragma unroll
    for (int kk = 0; kk < 9; ++kk) {
        unsigned short h[8];
        #pragma unroll
        for (int j = 0; j < 8; ++j) h[j] = f2b(xs[(size_t)(kk * 32 + j) * HW]);
        frag[kk] = *(const bf16x8*)h;
    }

    f32x4 acc[9];
    #pragma unroll
    for (int j = 0; j < 9; ++j) acc[j] = (f32x4)0.0f;

    // stage one W slice: 18 contiguous 1KB segments; waves issue 5,5,4,4
    #define STAGE_W1(KK, DST) do {                                             \
        for (int s = wave; s < 18; s += 4)                                     \
            GLDS(WiT + (size_t)(KK) * 9216 + s * 512 + lane * 8,               \
                 (DST) + s * 1024);                                            \
    } while (0)

    #define GSTEP1(KK, BUF) do {                                               \
        _Pragma("unroll")                                                      \
        for (int j = 0; j < 9; ++j) {                                          \
            const int wr = chh * 144 + j * 16 + r;                             \
            const bf16x8 wf = *(const bf16x8*)((BUF) + wr * 64 +               \
                                 ((q ^ ((wr >> 1) & 3)) * 16));                \
            acc[j] = mfma16(wf, frag[KK], acc[j]);                             \
        }                                                                      \
    } while (0)

    STAGE_W1(0, smc);
    SFENCE;
    asm volatile("s_waitcnt vmcnt(0)" ::: "memory");
    SFENCE;
    __builtin_amdgcn_s_barrier();
    SFENCE;
    #pragma unroll
    for (int kk = 0; kk < 8; ++kk) {
        STAGE_W1(kk + 1, smc + ((kk + 1) & 1) * WSL);
        SFENCE;
        if (wave < 2) { asm volatile("s_waitcnt vmcnt(5)" ::: "memory"); }
        else          { asm volatile("s_waitcnt vmcnt(4)" ::: "memory"); }
        SFENCE;
        __builtin_amdgcn_s_barrier();
        SFENCE;
        GSTEP1(kk, smc + (kk & 1) * WSL);
        SFENCE;
        __builtin_amdgcn_s_barrier();
        SFENCE;
    }
    asm volatile("s_waitcnt vmcnt(0)" ::: "memory");
    SFENCE;
    __builtin_amdgcn_s_barrier();
    SFENCE;
    GSTEP1(8, smc);
    __syncthreads();

    // ================= epilogue =================
    // LDS reuse: [0, 18432) = 32 rows x 576 B output staging,
    //            [34560, 36864) = 576-float stats accumulator.
    float* sstat = (float*)(smc + 34560);
    for (int c2 = tid; c2 < 576; c2 += 256) sstat[c2] = 0.0f;
    __syncthreads();

    #pragma unroll 1
    for (int j = 0; j < 9; ++j) {
        const int cb = chh * 144 + j * 16 + q * 4;
        const float4 b4 = *(const float4*)(bi + cb);
        float v[4];
        v[0] = fmaxf(acc[j][0] + b4.x, 0.0f);
        v[1] = fmaxf(acc[j][1] + b4.y, 0.0f);
        v[2] = fmaxf(acc[j][2] + b4.z, 0.0f);
        v[3] = fmaxf(acc[j][3] + b4.w, 0.0f);
        unsigned short h[4] = {f2b(v[0]), f2b(v[1]), f2b(v[2]), f2b(v[3])};
        *(uint2*)(smc + (pxh * 16 + r) * 576 + cb * 2) = *(const uint2*)h;
        float a1[4] = {v[0], v[1], v[2], v[3]};
        float a2[4] = {v[0]*v[0], v[1]*v[1], v[2]*v[2], v[3]*v[3]};
        #pragma unroll
        for (int m = 1; m < 16; m <<= 1) {
            #pragma unroll
            for (int i = 0; i < 4; ++i) {
                a1[i] += __shfl_xor(a1[i], m, 64);
                a2[i] += __shfl_xor(a2[i], m, 64);
            }
        }
        if (r == 0) {
            #pragma unroll
            for (int i = 0; i < 4; ++i) {
                atomicAdd(&sstat[cb + i], a1[i]);
                atomicAdd(&sstat[288 + cb + i], a2[i]);
            }
        }
    }
    __syncthreads();

    // ---- store 32x288 tile to tmpT (tiled+swizzled) + slotted stats flush ----
    for (int idx = tid; idx < 1152; idx += 256) {
        const int row = idx / 36;
        const int off = idx - row * 36;
        const int kk  = off >> 2;
        const int p   = off & 3;
        const int slot = p ^ ((row >> 1) & 3);
        *(uint4*)(tmpT + (size_t)blockIdx.x * 9216 + kk * 1024 + row * 32 + slot * 8) =
            *(const uint4*)(smc + row * 576 + off * 16);
    }
    float* slot = slots + (size_t)(blockIdx.x & (NSLOT - 1)) * 576;
    for (int c2 = tid; c2 < 576; c2 += 256)
        atomicAdd(&slot[c2], sstat[c2]);
}

// ---------------------------------------------------------------------------
// K2a: reduce 64 stat slots -> BN scale/shift. 576 threads (9 waves).
// ---------------------------------------------------------------------------
__global__ __launch_bounds__(576) void k_scale(const float* __restrict__ slots,
                                               const float* __restrict__ gamma,
                                               const float* __restrict__ beta,
                                               float* __restrict__ scale,
                                               float* __restrict__ shift) {
    __shared__ float red[576];
    const int tid = threadIdx.x;
    float s = 0.0f;
    #pragma unroll 4
    for (int sl = 0; sl < NSLOT; ++sl) s += slots[sl * 576 + tid];
    red[tid] = s;
    __syncthreads();
    if (tid < CH) {
        const float inv  = 1.0f / (float)(NB * HW);
        const float mean = red[tid] * inv;
        const float var  = red[288 + tid] * inv - mean * mean;
        const float rs   = rsqrtf(var + BN_EPS);
        const float sc   = gamma[tid] * rs;
        scale[tid] = sc;
        shift[tid] = beta[tid] - mean * sc;
    }
}

// ---------------------------------------------------------------------------
// K2b: WosT[tiled] = bf16(Wo*scale); bo2[m] = bo[m] + Wo[m][:]@shift
// (overwrites the stat slots -- runs after k_scale)
// ---------------------------------------------------------------------------
__global__ __launch_bounds__(64) void k_fold(const float* __restrict__ Wo,
                                             const float* __restrict__ bo,
                                             const float* __restrict__ scale,
                                             const float* __restrict__ shift,
                                             unsigned short* __restrict__ WosT,
                                             float* __restrict__ bo2) {
    const int m = blockIdx.x;
    const int t = threadIdx.x;
    float s = 0.0f;
    for (int k = t; k < CH; k += 64) s += Wo[(size_t)m * CH + k] * shift[k];
    #pragma unroll
    for (int off = 32; off > 0; off >>= 1) s += __shfl_down(s, off, 64);
    if (t == 0) bo2[m] = bo[m] + s;

    if (t < 36) {
        const int kk   = t >> 2;
        const int slot = t & 3;
        const int c0   = kk * 32 + ((slot ^ ((m >> 1) & 3)) << 3);
        unsigned short h[8];
        #pragma unroll
        for (int j = 0; j < 8; ++j)
            h[j] = f2b(Wo[(size_t)m * CH + c0 + j] * scale[c0 + j]);
        *(uint4*)(WosT + (size_t)kk * 9216 + m * 32 + slot * 8) = *(const uint4*)h;
    }
}

// ---------------------------------------------------------------------------
// K3: pipelined MFMA GEMM2 (ker = Wos @ tmp + bo2) -> kerL -> involution.
// Block: 64 px (one image row) x 288 ker-ch, 4 waves; wave = 32 px x 144 c.
// Both operands staged via contiguous-1KB GLDS from tiled layouts.
// Phase boundaries pinned with sched_barrier(0).
// ---------------------------------------------------------------------------
#define BUF2 22528
#define KLS2 68
__global__ __launch_bounds__(256) void k_gemm2_invol(const unsigned short* __restrict__ tmpT,
                                                     const unsigned short* __restrict__ WosT,
                                                     const float* __restrict__ bo2,
                                                     const float* __restrict__ x,
                                                     float* __restrict__ out) {
    __shared__ char smc[2 * BUF2];   // 45056 B; kerL reuses [0, 39168)
    unsigned short* kerL = (unsigned short*)smc;

    const int tid  = threadIdx.x;
    const int wave = tid >> 6;
    const int lane = tid & 63;
    const int q    = lane >> 4;
    const int r    = lane & 15;
    const int pxh  = wave & 1;
    const int chh  = wave >> 1;
    const int b    = blockIdx.y;
    const int h    = blockIdx.x;
    const int P0   = b * 128 + h * 2;   // first 32-px tile of this row

    f32x4 acc[2][9];
    #pragma unroll
    for (int t = 0; t < 2; ++t)
        #pragma unroll
        for (int j = 0; j < 9; ++j) acc[t][j] = (f32x4)0.0f;

    // stage one BK=32 slice: 22 contiguous 1KB segments (4 X + 18 W);
    // waves issue 6,6,5,5.
    #define STAGE2(KK, DST) do {                                               \
        for (int s = wave; s < 22; s += 4) {                                   \
            const unsigned short* g = (s < 4)                                  \
                ? tmpT + (size_t)(P0 + (s >> 1)) * 9216 + (KK) * 1024          \
                       + (s & 1) * 512 + lane * 8                              \
                : WosT + (size_t)(KK) * 9216 + (s - 4) * 512 + lane * 8;       \
            GLDS(g, (DST) + s * 1024);                                         \
        }                                                                      \
    } while (0)

    #define GSTEP2(BUF) do {                                                   \
        bf16x8 xf0, xf1;                                                       \
        { const int xr = pxh * 32 + r;                                         \
          xf0 = *(const bf16x8*)((BUF) + xr * 64 +                             \
                     ((q ^ ((xr >> 1) & 3)) * 16)); }                          \
        { const int xr = pxh * 32 + 16 + r;                                    \
          xf1 = *(const bf16x8*)((BUF) + xr * 64 +                             \
                     ((q ^ ((xr >> 1) & 3)) * 16)); }                          \
        _Pragma("unroll")                                                      \
        for (int j = 0; j < 9; ++j) {                                          \
            const int wr = 64 + chh * 144 + j * 16 + r;                        \
            const bf16x8 wf = *(const bf16x8*)((BUF) + wr * 64 +               \
                                 ((q ^ ((wr >> 1) & 3)) * 16));                \
            acc[0][j] = mfma16(wf, xf0, acc[0][j]);                            \
            acc[1][j] = mfma16(wf, xf1, acc[1][j]);                            \
        }                                                                      \
    } while (0)

    STAGE2(0, smc);
    SFENCE;
    asm volatile("s_waitcnt vmcnt(0)" ::: "memory");
    SFENCE;
    __builtin_amdgcn_s_barrier();
    SFENCE;
    #pragma unroll 1
    for (int kk = 0; kk < 8; ++kk) {
        STAGE2(kk + 1, smc + ((kk + 1) & 1) * BUF2);
        SFENCE;
        if (wave < 2) { asm volatile("s_waitcnt vmcnt(6)" ::: "memory"); }
        else          { asm volatile("s_waitcnt vmcnt(5)" ::: "memory"); }
        SFENCE;
        __builtin_amdgcn_s_barrier();
        SFENCE;
        GSTEP2(smc + (kk & 1) * BUF2);
        SFENCE;
        __builtin_amdgcn_s_barrier();
        SFENCE;
    }
    asm volatile("s_waitcnt vmcnt(0)" ::: "memory");
    SFENCE;
    __builtin_amdgcn_s_barrier();
    SFENCE;
    GSTEP2(smc);
    __syncthreads();

    // ---- stage ker tile to LDS: kerL[ch][px], 288 x 64 (stride 68) ----
    #pragma unroll
    for (int j = 0; j < 9; ++j) {
        const int cb = chh * 144 + j * 16 + q * 4;
        const float4 bz = *(const float4*)(bo2 + cb);
        #pragma unroll
        for (int t = 0; t < 2; ++t) {
            const int pxl = pxh * 32 + t * 16 + r;
            kerL[(cb + 0) * KLS2 + pxl] = f2b(acc[t][j][0] + bz.x);
            kerL[(cb + 1) * KLS2 + pxl] = f2b(acc[t][j][1] + bz.y);
            kerL[(cb + 2) * KLS2 + pxl] = f2b(acc[t][j][2] + bz.z);
            kerL[(cb + 3) * KLS2 + pxl] = f2b(acc[t][j][3] + bz.w);
        }
    }
    __syncthreads();

    // ---- involution: 256 threads, 16 ch x 64 w per iteration, 18 iters ----
    const int tm = tid >> 4;
    const int tn = tid & 15;
    const int wb = tn * 4;
    #pragma unroll 1
    for (int i = 0; i < 18; ++i) {
        const int ch = tm + 16 * i;
        const int cb = (ch / CPG) * CPG;
        float xv[3][6];
        #pragma unroll
        for (int dr = 0; dr < 3; ++dr) {
            const int hh = h + dr - 1;
            const bool rv = (hh >= 0) && (hh < IMH);
            const float* xr2 = x + ((size_t)(b * CH + ch) * IMH + (rv ? hh : 0)) * IMW;
            if (rv) {
                const float4 m4 = *(const float4*)(xr2 + wb);
                xv[dr][1] = m4.x; xv[dr][2] = m4.y; xv[dr][3] = m4.z; xv[dr][4] = m4.w;
                xv[dr][0] = (wb > 0)       ? xr2[wb - 1] : 0.0f;
                xv[dr][5] = (wb + 4 < IMW) ? xr2[wb + 4] : 0.0f;
            } else {
                #pragma unroll
                for (int j = 0; j < 6; ++j) xv[dr][j] = 0.0f;
            }
        }
        float o[4] = {0.0f, 0.0f, 0.0f, 0.0f};
        #pragma unroll
        for (int k = 0; k < 9; ++k) {
            const int dr = k / 3, dc = k % 3;
            const uint2 kk = *(const uint2*)(kerL + (cb + k) * KLS2 + tn * 4);
            const unsigned short* ks = (const unsigned short*)&kk;
            #pragma unroll
            for (int j = 0; j < 4; ++j)
                o[j] += b2f(ks[j]) * xv[dr][j + dc];
        }
        float4 ov = {o[0], o[1], o[2], o[3]};
        *(float4*)(out + ((size_t)(b * CH + ch) * IMH + h) * IMW + wb) = ov;
    }
}

// ---------------------------------------------------------------------------
extern "C" void kernel_launch(void* const* d_in, const int* in_sizes, int n_in,
                              void* d_out, int out_size, void* d_ws, size_t ws_size,
                              hipStream_t stream) {
    const float* x     = (const float*)d_in[0];
    const float* Wi    = (const float*)d_in[1];
    const float* bi    = (const float*)d_in[2];
    const float* gamma = (const float*)d_in[3];
    const float* beta  = (const float*)d_in[4];
    const float* Wo    = (const float*)d_in[5];
    const float* bo    = (const float*)d_in[6];
    float* out = (float*)d_out;

    char* ws = (char*)d_ws;
    unsigned short* tmpT = (unsigned short*)(ws + TT_OFF);
    unsigned short* WiT  = (unsigned short*)(ws + WIB_OFF);
    unsigned short* WosT = (unsigned short*)(ws + WOS_OFF);
    float* slots = (float*)(ws + WOS_OFF);      // stat slots, pre-k_fold
    float* scale = (float*)(ws + SC_OFF);
    float* shift = (float*)(ws + SH_OFF);
    float* bo2   = (float*)(ws + BO2_OFF);

    k_cvt_wi<<<dim3(41), 256, 0, stream>>>(Wi, WiT);
    hipMemsetAsync(ws + WOS_OFF, 0, NSLOT * 576 * sizeof(float), stream);
    k_gemm1<<<dim3(NPX / 32), 256, 0, stream>>>(WiT, bi, x, tmpT, slots);
    k_scale<<<dim3(1), 576, 0, stream>>>(slots, gamma, beta, scale, shift);
    k_fold<<<dim3(CH), 64, 0, stream>>>(Wo, bo, scale, shift, WosT, bo2);
    k_gemm2_invol<<<dim3(HW / 64, NB), 256, 0, stream>>>(tmpT, WosT, bo2, x, out);
}